// Round 1
// baseline (140.887 us; speedup 1.0000x reference)
//
#include <hip/hip_runtime.h>
#include <math.h>

typedef float fx4 __attribute__((ext_vector_type(4)));

#define TM    64      // rows per block
#define TN    128     // 64 gate cols + 64 noise cols
#define KC    32      // K chunk staged in LDS
#define DDIM  2048
#define ENUM  64

__global__ __launch_bounds__(256)
void noisy_topk_kernel(const float* __restrict__ x,
                       const float* __restrict__ eps,
                       const float* __restrict__ Wg,
                       const float* __restrict__ gb,
                       const float* __restrict__ Wn,
                       const float* __restrict__ nb,
                       float* __restrict__ out)
{
    __shared__ float xs[KC][TM];         // 8 KB, [k][row]
    __shared__ float ws[KC][TN];         // 16 KB, [k][col]
    __shared__ float hbuf[TM][TN + 4];   // ~33.8 KB, padded for bank spread
    __shared__ float pv1[TM][4], pv2[TM][4];
    __shared__ int   pi1[TM][4], pi2[TM][4];
    __shared__ float tp1[TM], tp2[TM];
    __shared__ int   ti1[TM], ti2[TM];

    const int tid  = threadIdx.x;
    const int row0 = blockIdx.x * TM;

    // ---- staging thread mapping ----
    const int xrow = tid & 63;           // which row this thread stages
    const int xq   = tid >> 6;           // 0..3 -> k offset xq*8
    const int wc   = tid & 127;          // which weight col (0..63 gate, 64..127 noise)
    const int wq   = tid >> 7;           // 0..1 -> k offset wq*16

    const float* xp = x + (size_t)(row0 + xrow) * DDIM + xq * 8;
    const float* wrow = (wc < ENUM) ? (Wg + (size_t)wc * DDIM)
                                    : (Wn + (size_t)(wc - ENUM) * DDIM);
    const float* wp = wrow + wq * 16;

    // ---- prefetch first chunk into registers ----
    fx4 xr0 = *(const fx4*)(xp + 0);
    fx4 xr1 = *(const fx4*)(xp + 4);
    fx4 wr0 = *(const fx4*)(wp + 0);
    fx4 wr1 = *(const fx4*)(wp + 4);
    fx4 wr2 = *(const fx4*)(wp + 8);
    fx4 wr3 = *(const fx4*)(wp + 12);

    // ---- compute thread mapping: 16 row-groups x 16 col-groups ----
    const int rg = tid >> 4;             // rows rg*4 .. rg*4+3
    const int cg = tid & 15;             // cols cg*8 .. cg*8+7

    float acc[4][8];
    #pragma unroll
    for (int i = 0; i < 4; ++i)
        #pragma unroll
        for (int j = 0; j < 8; ++j) acc[i][j] = 0.f;

    for (int k0 = 0; k0 < DDIM; k0 += KC) {
        __syncthreads();   // previous compute done: safe to overwrite LDS
        #pragma unroll
        for (int j = 0; j < 4; ++j) xs[xq*8 + j][xrow]     = xr0[j];
        #pragma unroll
        for (int j = 0; j < 4; ++j) xs[xq*8 + 4 + j][xrow] = xr1[j];
        #pragma unroll
        for (int j = 0; j < 4; ++j) ws[wq*16 + j][wc]      = wr0[j];
        #pragma unroll
        for (int j = 0; j < 4; ++j) ws[wq*16 + 4 + j][wc]  = wr1[j];
        #pragma unroll
        for (int j = 0; j < 4; ++j) ws[wq*16 + 8 + j][wc]  = wr2[j];
        #pragma unroll
        for (int j = 0; j < 4; ++j) ws[wq*16 + 12 + j][wc] = wr3[j];
        __syncthreads();   // staged data visible

        // prefetch next chunk (overlaps with compute below)
        if (k0 + KC < DDIM) {
            xr0 = *(const fx4*)(xp + k0 + KC + 0);
            xr1 = *(const fx4*)(xp + k0 + KC + 4);
            wr0 = *(const fx4*)(wp + k0 + KC + 0);
            wr1 = *(const fx4*)(wp + k0 + KC + 4);
            wr2 = *(const fx4*)(wp + k0 + KC + 8);
            wr3 = *(const fx4*)(wp + k0 + KC + 12);
        }

        #pragma unroll
        for (int k = 0; k < KC; ++k) {
            fx4 xa = *(const fx4*)&xs[k][rg * 4];
            fx4 wa = *(const fx4*)&ws[k][cg * 8];
            fx4 wb = *(const fx4*)&ws[k][cg * 8 + 4];
            #pragma unroll
            for (int i = 0; i < 4; ++i) {
                #pragma unroll
                for (int j = 0; j < 4; ++j) {
                    acc[i][j]     = fmaf(xa[i], wa[j], acc[i][j]);
                    acc[i][j + 4] = fmaf(xa[i], wb[j], acc[i][j + 4]);
                }
            }
        }
    }

    // ---- dump C tile to LDS ----
    #pragma unroll
    for (int i = 0; i < 4; ++i) {
        fx4 lo, hi;
        #pragma unroll
        for (int j = 0; j < 4; ++j) { lo[j] = acc[i][j]; hi[j] = acc[i][j + 4]; }
        *(fx4*)&hbuf[rg * 4 + i][cg * 8]     = lo;
        *(fx4*)&hbuf[rg * 4 + i][cg * 8 + 4] = hi;
    }
    __syncthreads();

    // ---- epilogue: h = gate + eps * softplus(noise); partial top-2 (4 threads/row) ----
    const int rloc = tid >> 2;   // 0..63
    const int q    = tid & 3;    // expert range q*16 .. q*16+15
    {
        float v1 = -INFINITY, v2 = -INFINITY;
        int   i1 = -1, i2 = -1;
        const float* ep = eps + (size_t)(row0 + rloc) * ENUM + q * 16;
        #pragma unroll
        for (int v = 0; v < 4; ++v) {
            fx4 gv  = *(const fx4*)&hbuf[rloc][q * 16 + v * 4];
            fx4 nv  = *(const fx4*)&hbuf[rloc][ENUM + q * 16 + v * 4];
            fx4 ev  = *(const fx4*)(ep + v * 4);
            fx4 gbv = *(const fx4*)(gb + q * 16 + v * 4);
            fx4 nbv = *(const fx4*)(nb + q * 16 + v * 4);
            #pragma unroll
            for (int j = 0; j < 4; ++j) {
                float nz = nv[j] + nbv[j];
                // stable softplus: max(x,0) + log1p(exp(-|x|))
                float sp = fmaxf(nz, 0.f) + log1pf(expf(-fabsf(nz)));
                float h  = gv[j] + gbv[j] + ev[j] * sp;
                int   e  = q * 16 + v * 4 + j;
                if (h > v1)      { v2 = v1; i2 = i1; v1 = h; i1 = e; }
                else if (h > v2) { v2 = h;  i2 = e; }
            }
        }
        pv1[rloc][q] = v1; pv2[rloc][q] = v2;
        pi1[rloc][q] = i1; pi2[rloc][q] = i2;
    }
    __syncthreads();

    // ---- merge partials (1 thread/row), softmax over top-2 ----
    if (tid < TM) {
        float v1 = -INFINITY, v2 = -INFINITY;
        int   i1 = -1, i2 = -1;
        #pragma unroll
        for (int qq = 0; qq < 4; ++qq) {
            float a1 = pv1[tid][qq]; int b1 = pi1[tid][qq];
            float a2 = pv2[tid][qq]; int b2 = pi2[tid][qq];
            if (a1 > v1)      { v2 = v1; i2 = i1; v1 = a1; i1 = b1; }
            else if (a1 > v2) { v2 = a1; i2 = b1; }
            if (a2 > v1)      { v2 = v1; i2 = i1; v1 = a2; i1 = b2; }
            else if (a2 > v2) { v2 = a2; i2 = b2; }
        }
        float e2  = expf(v2 - v1);       // <= 1
        float inv = 1.f / (1.f + e2);
        tp1[tid] = inv;                  // prob at i1
        tp2[tid] = e2 * inv;             // prob at i2
        ti1[tid] = i1; ti2[tid] = i2;
    }
    __syncthreads();

    // ---- coalesced output write: 64 floats per row, zeros except top-2 ----
    {
        const int   orow = tid >> 2;
        const int   oq   = tid & 3;
        const int   a1 = ti1[orow], a2 = ti2[orow];
        const float p1 = tp1[orow], p2 = tp2[orow];
        float* op = out + (size_t)(row0 + orow) * ENUM + oq * 16;
        #pragma unroll
        for (int v = 0; v < 4; ++v) {
            fx4 o;
            #pragma unroll
            for (int j = 0; j < 4; ++j) {
                int e = oq * 16 + v * 4 + j;
                o[j] = (e == a1) ? p1 : ((e == a2) ? p2 : 0.f);
            }
            *(fx4*)(op + v * 4) = o;
        }
    }
}

extern "C" void kernel_launch(void* const* d_in, const int* in_sizes, int n_in,
                              void* d_out, int out_size, void* d_ws, size_t ws_size,
                              hipStream_t stream) {
    const float* x   = (const float*)d_in[0];
    const float* eps = (const float*)d_in[1];
    const float* Wg  = (const float*)d_in[2];
    const float* gbp = (const float*)d_in[3];
    const float* Wn  = (const float*)d_in[4];
    const float* nbp = (const float*)d_in[5];
    float* out = (float*)d_out;

    const int M = in_sizes[0] / DDIM;    // B*T = 16384
    dim3 grid(M / TM), block(256);
    hipLaunchKernelGGL(noisy_topk_kernel, grid, block, 0, stream,
                       x, eps, Wg, gbp, Wn, nbp, out);
}

// Round 3
// 133.580 us; speedup vs baseline: 1.0547x; 1.0547x over previous
//
#include <hip/hip_runtime.h>
#include <math.h>

typedef float fx4 __attribute__((ext_vector_type(4)));

#define TM    32      // rows per block
#define TN    128     // 64 gate cols + 64 noise cols
#define KC    32      // K chunk staged in LDS
#define DDIM  2048
#define ENUM  64
#define NC    (DDIM / KC)   // 64 chunks

__global__ __launch_bounds__(256, 2)
void noisy_topk_kernel(const float* __restrict__ x,
                       const float* __restrict__ eps,
                       const float* __restrict__ Wg,
                       const float* __restrict__ gb,
                       const float* __restrict__ Wn,
                       const float* __restrict__ nb,
                       float* __restrict__ out)
{
    __shared__ float xs[2][KC][TM];      // 8 KB  [buf][k][row]
    __shared__ float ws[2][KC][TN];      // 32 KB [buf][k][col]
    __shared__ float hbuf[TM][TN + 4];   // 16.9 KB
    __shared__ float pv1[TM][8], pv2[TM][8];
    __shared__ int   pi1[TM][8], pi2[TM][8];
    __shared__ float tp1[TM], tp2[TM];
    __shared__ int   ti1[TM], ti2[TM];

    const int tid  = threadIdx.x;
    const int row0 = blockIdx.x * TM;

    // ---- staging thread mapping ----
    const int xrow = tid & 31;           // row this thread stages
    const int xq   = tid >> 5;           // 0..7 -> k offset xq*4
    const int wc   = tid & 127;          // weight col (0..63 gate, 64..127 noise)
    const int wq   = tid >> 7;           // 0..1 -> k offset wq*16

    const float* xp   = x + (size_t)(row0 + xrow) * DDIM + xq * 4;
    const float* wrow = (wc < ENUM) ? (Wg + (size_t)wc * DDIM)
                                    : (Wn + (size_t)(wc - ENUM) * DDIM);
    const float* wp   = wrow + wq * 16;

    // ---- compute mapping: wave footprint 8 rg x 8 cg (min unique LDS bytes) ----
    // tid bits: cg = {b7b6, b2b1b0}, rg = {b5b4b3}  -> each wave covers 8x8
    const int rg = (tid >> 3) & 7;               // rows rg*4 .. rg*4+3
    const int cg = (tid & 7) | ((tid >> 6) << 3);// cols cg*4 .. cg*4+3

    float acc[4][4];
    #pragma unroll
    for (int i = 0; i < 4; ++i)
        #pragma unroll
        for (int j = 0; j < 4; ++j) acc[i][j] = 0.f;

    // ---- prologue: stage chunk 0, prefetch chunk 1 ----
    fx4 xr  = *(const fx4*)(xp);
    fx4 wr0 = *(const fx4*)(wp + 0);
    fx4 wr1 = *(const fx4*)(wp + 4);
    fx4 wr2 = *(const fx4*)(wp + 8);
    fx4 wr3 = *(const fx4*)(wp + 12);
    #pragma unroll
    for (int j = 0; j < 4; ++j) xs[0][xq*4 + j][xrow]      = xr[j];
    #pragma unroll
    for (int j = 0; j < 4; ++j) ws[0][wq*16 + j][wc]       = wr0[j];
    #pragma unroll
    for (int j = 0; j < 4; ++j) ws[0][wq*16 + 4 + j][wc]   = wr1[j];
    #pragma unroll
    for (int j = 0; j < 4; ++j) ws[0][wq*16 + 8 + j][wc]   = wr2[j];
    #pragma unroll
    for (int j = 0; j < 4; ++j) ws[0][wq*16 + 12 + j][wc]  = wr3[j];
    xr  = *(const fx4*)(xp + KC);
    wr0 = *(const fx4*)(wp + KC + 0);
    wr1 = *(const fx4*)(wp + KC + 4);
    wr2 = *(const fx4*)(wp + KC + 8);
    wr3 = *(const fx4*)(wp + KC + 12);
    __syncthreads();

    for (int c = 0; c < NC; ++c) {
        const int cur = c & 1;
        const int nxt = cur ^ 1;

        // stage chunk c+1 (regs loaded last iter) into the other buffer
        if (c + 1 < NC) {
            #pragma unroll
            for (int j = 0; j < 4; ++j) xs[nxt][xq*4 + j][xrow]     = xr[j];
            #pragma unroll
            for (int j = 0; j < 4; ++j) ws[nxt][wq*16 + j][wc]      = wr0[j];
            #pragma unroll
            for (int j = 0; j < 4; ++j) ws[nxt][wq*16 + 4 + j][wc]  = wr1[j];
            #pragma unroll
            for (int j = 0; j < 4; ++j) ws[nxt][wq*16 + 8 + j][wc]  = wr2[j];
            #pragma unroll
            for (int j = 0; j < 4; ++j) ws[nxt][wq*16 + 12 + j][wc] = wr3[j];
        }
        // prefetch chunk c+2 from global (latency hidden under compute)
        if (c + 2 < NC) {
            const int ko = (c + 2) * KC;
            xr  = *(const fx4*)(xp + ko);
            wr0 = *(const fx4*)(wp + ko + 0);
            wr1 = *(const fx4*)(wp + ko + 4);
            wr2 = *(const fx4*)(wp + ko + 8);
            wr3 = *(const fx4*)(wp + ko + 12);
        }

        // compute chunk c, software-pipelined fragment loads
        const float* xsb = &xs[cur][0][0];
        const float* wsb = &ws[cur][0][0];
        fx4 xa = *(const fx4*)(xsb + rg * 4);
        fx4 wa = *(const fx4*)(wsb + cg * 4);
        #pragma unroll
        for (int k = 0; k < KC; ++k) {
            fx4 xan, wan;
            if (k + 1 < KC) {
                xan = *(const fx4*)(xsb + (k + 1) * TM + rg * 4);
                wan = *(const fx4*)(wsb + (k + 1) * TN + cg * 4);
            }
            #pragma unroll
            for (int i = 0; i < 4; ++i)
                #pragma unroll
                for (int j = 0; j < 4; ++j)
                    acc[i][j] = fmaf(xa[i], wa[j], acc[i][j]);
            xa = xan; wa = wan;
        }
        __syncthreads();
    }

    // ---- dump C tile to LDS ----
    #pragma unroll
    for (int i = 0; i < 4; ++i) {
        fx4 o;
        #pragma unroll
        for (int j = 0; j < 4; ++j) o[j] = acc[i][j];
        *(fx4*)&hbuf[rg * 4 + i][cg * 4] = o;
    }
    __syncthreads();

    // ---- epilogue: h = gate + eps*softplus(noise); partial top-2 (8 threads/row) ----
    const int rloc = tid >> 3;   // 0..31
    const int q    = tid & 7;    // expert range q*8 .. q*8+7
    {
        float v1 = -INFINITY, v2 = -INFINITY;
        int   i1 = -1, i2 = -1;
        const float* ep = eps + (size_t)(row0 + rloc) * ENUM + q * 8;
        #pragma unroll
        for (int v = 0; v < 2; ++v) {
            fx4 gv  = *(const fx4*)&hbuf[rloc][q * 8 + v * 4];
            fx4 nv  = *(const fx4*)&hbuf[rloc][ENUM + q * 8 + v * 4];
            fx4 ev  = *(const fx4*)(ep + v * 4);
            fx4 gbv = *(const fx4*)(gb + q * 8 + v * 4);
            fx4 nbv = *(const fx4*)(nb + q * 8 + v * 4);
            #pragma unroll
            for (int j = 0; j < 4; ++j) {
                float nz = nv[j] + nbv[j];
                float sp = fmaxf(nz, 0.f) + log1pf(expf(-fabsf(nz)));
                float h  = gv[j] + gbv[j] + ev[j] * sp;
                int   e  = q * 8 + v * 4 + j;
                if (h > v1)      { v2 = v1; i2 = i1; v1 = h; i1 = e; }
                else if (h > v2) { v2 = h;  i2 = e; }
            }
        }
        pv1[rloc][q] = v1; pv2[rloc][q] = v2;
        pi1[rloc][q] = i1; pi2[rloc][q] = i2;
    }
    __syncthreads();

    // ---- merge partials (1 thread/row), softmax over top-2 ----
    if (tid < TM) {
        float v1 = -INFINITY, v2 = -INFINITY;
        int   i1 = -1, i2 = -1;
        #pragma unroll
        for (int qq = 0; qq < 8; ++qq) {
            float a1 = pv1[tid][qq]; int b1 = pi1[tid][qq];
            float a2 = pv2[tid][qq]; int b2 = pi2[tid][qq];
            if (a1 > v1)      { v2 = v1; i2 = i1; v1 = a1; i1 = b1; }
            else if (a1 > v2) { v2 = a1; i2 = b1; }
            if (a2 > v1)      { v2 = v1; i2 = i1; v1 = a2; i1 = b2; }
            else if (a2 > v2) { v2 = a2; i2 = b2; }
        }
        float e2  = expf(v2 - v1);
        float inv = 1.f / (1.f + e2);
        tp1[tid] = inv;
        tp2[tid] = e2 * inv;
        ti1[tid] = i1; ti2[tid] = i2;
    }
    __syncthreads();

    // ---- coalesced output write ----
    {
        const int   orow = tid >> 3;
        const int   oq   = tid & 7;
        const int   a1 = ti1[orow], a2 = ti2[orow];
        const float p1 = tp1[orow], p2 = tp2[orow];
        float* op = out + (size_t)(row0 + orow) * ENUM + oq * 8;
        #pragma unroll
        for (int v = 0; v < 2; ++v) {
            fx4 o;
            #pragma unroll
            for (int j = 0; j < 4; ++j) {
                int e = oq * 8 + v * 4 + j;
                o[j] = (e == a1) ? p1 : ((e == a2) ? p2 : 0.f);
            }
            *(fx4*)(op + v * 4) = o;
        }
    }
}

extern "C" void kernel_launch(void* const* d_in, const int* in_sizes, int n_in,
                              void* d_out, int out_size, void* d_ws, size_t ws_size,
                              hipStream_t stream) {
    const float* x   = (const float*)d_in[0];
    const float* eps = (const float*)d_in[1];
    const float* Wg  = (const float*)d_in[2];
    const float* gbp = (const float*)d_in[3];
    const float* Wn  = (const float*)d_in[4];
    const float* nbp = (const float*)d_in[5];
    float* out = (float*)d_out;

    const int M = in_sizes[0] / DDIM;    // B*T = 16384
    dim3 grid(M / TM), block(256);
    hipLaunchKernelGGL(noisy_topk_kernel, grid, block, 0, stream,
                       x, eps, Wg, gbp, Wn, nbp, out);
}